// Round 2
// baseline (54.978 us; speedup 1.0000x reference)
//
#include <hip/hip_runtime.h>
#include <math.h>

#define NB 8
#define ND 64
#define NS 512
#define TI 16

// Kernel 1: a[b,j,k] = sum_d x[b,d,j] * W[d,k]
//           bm[b,j,k] = sum_d x[b,d,j] * W[64+d,k]
__global__ __launch_bounds__(ND) void k_ab(const float* __restrict__ x,
                                           const float* __restrict__ W,
                                           float* __restrict__ a_ws,
                                           float* __restrict__ b_ws) {
    int bj = blockIdx.x;          // 0..B*S-1
    int b  = bj >> 9;             // /512
    int j  = bj & (NS - 1);
    int k  = threadIdx.x;         // 0..63
    const float* xp = x + (size_t)(b * ND) * NS + j;
    float av = 0.f, bv = 0.f;
#pragma unroll
    for (int d = 0; d < ND; ++d) {
        float xv = xp[(size_t)d * NS];
        av = fmaf(xv, W[d * ND + k], av);
        bv = fmaf(xv, W[(ND + d) * ND + k], bv);
    }
    a_ws[(size_t)bj * ND + k] = av;
    b_ws[(size_t)bj * ND + k] = bv;
}

// Kernel 2: fused wmat + c GEMM.
// Block owns c[b, 0:64, i0:i0+TI]. Loops over w in tiles of 64:
//   wm[w][i] = (i0+i <= w0+w) ? 1 - ||a[b,i0+i,:]+bm[b,w0+w,:]|| : 1
//   acc[d][i] += x[b,d,w0+w] * wm[w][i]
__global__ __launch_bounds__(256) void k_c(const float* __restrict__ x,
                                           const float* __restrict__ a_ws,
                                           const float* __restrict__ b_ws,
                                           float* __restrict__ c) {
    __shared__ float a_t[TI][ND + 1];     // a[i][k], pad -> bank = (i+k)%32
    __shared__ float b_t[64][ND + 1];     // b[w][k]
    __shared__ float x_t[ND][64 + 1];     // x[d][w]
    __shared__ float wm[64][TI];          // wmat[w][i]

    int b  = blockIdx.y;
    int i0 = blockIdx.x * TI;
    int t  = threadIdx.x;                 // 0..255

    // stage a tile: TI*64 = 1024 elements, 4 per thread, coalesced in k
#pragma unroll
    for (int r = 0; r < 4; ++r) {
        int e = t + r * 256;
        int i = e >> 6;
        int k = e & 63;
        a_t[i][k] = a_ws[(size_t)(b * NS + i0 + i) * ND + k];
    }

    int i_loc  = t & (TI - 1);            // 0..15
    int d_base = t >> 4;                  // 0..15
    float acc[4] = {0.f, 0.f, 0.f, 0.f};

    for (int w0 = 0; w0 < NS; w0 += 64) {
        __syncthreads();  // previous-iter LDS consumers done (also covers a_t staging 1st iter)

        // stage b tile (64x64) and x tile (64x64): 16 elems per thread, coalesced
#pragma unroll
        for (int r = 0; r < 16; ++r) {
            int e = t + r * 256;
            int w = e >> 6;
            int k = e & 63;
            b_t[w][k] = b_ws[(size_t)(b * NS + w0 + w) * ND + k];
            // x_t[d][w]: d = e>>6, w-index = e&63, coalesced along S
            x_t[w][k] = x[(size_t)(b * ND + w) * NS + w0 + k];
        }
        __syncthreads();

        // compute wm[w][i]: 4 entries per thread
#pragma unroll
        for (int q = 0; q < 4; ++q) {
            int w = (t >> 4) + 16 * q;    // 0..63
            float v;
            if (i0 + i_loc <= w0 + w) {
                float s = 0.f;
#pragma unroll
                for (int k = 0; k < ND; ++k) {
                    float u = a_t[i_loc][k] + b_t[w][k];
                    s = fmaf(u, u, s);
                }
                v = 1.f - sqrtf(s);
            } else {
                v = 1.f;                  // masked region: wmat = 1 - 0
            }
            wm[w][i_loc] = v;
        }
        __syncthreads();

        // accumulate c over this w tile
#pragma unroll
        for (int w = 0; w < 64; ++w) {
            float wv = wm[w][i_loc];
#pragma unroll
            for (int r = 0; r < 4; ++r) {
                acc[r] = fmaf(x_t[d_base + 16 * r][w], wv, acc[r]);
            }
        }
    }

    // write out c[b][d][i0+i_loc]
#pragma unroll
    for (int r = 0; r < 4; ++r) {
        int d = d_base + 16 * r;
        c[(size_t)(b * ND + d) * NS + i0 + i_loc] = acc[r];
    }
}

extern "C" void kernel_launch(void* const* d_in, const int* in_sizes, int n_in,
                              void* d_out, int out_size, void* d_ws, size_t ws_size,
                              hipStream_t stream) {
    const float* x = (const float*)d_in[0];
    const float* W = (const float*)d_in[1];
    float* out  = (float*)d_out;
    float* a_ws = (float*)d_ws;
    float* b_ws = a_ws + (size_t)NB * NS * ND;

    k_ab<<<dim3(NB * NS), dim3(ND), 0, stream>>>(x, W, a_ws, b_ws);
    k_c<<<dim3(NS / TI, NB), dim3(256), 0, stream>>>(x, a_ws, b_ws, out);
}

// Round 3
// 37.606 us; speedup vs baseline: 1.4620x; 1.4620x over previous
//
#include <hip/hip_runtime.h>
#include <math.h>

#define NB 8
#define ND 64
#define NS 512
#define TI 16          // i-tile in k_c
#define JT 8           // j-tile in k_ab
#define PAD 68         // LDS row stride in floats (272 B -> 16B aligned, 2-way bank alias = free)

// ---------------------------------------------------------------------------
// Kernel 1: a[b,j,k] = sum_d x[b,d,j]*W[d,k] ; bm[b,j,k] = sum_d x[b,d,j]*W[64+d,k]
// Block: (j-tile of 8, b). W staged in LDS transposed [k][d] for float4 d-reads.
// ---------------------------------------------------------------------------
__global__ __launch_bounds__(256) void k_ab(const float* __restrict__ x,
                                            const float* __restrict__ W,
                                            float* __restrict__ a_ws,
                                            float* __restrict__ b_ws) {
    __shared__ __align__(16) float Ww_t[ND][PAD];   // [k][d]
    __shared__ __align__(16) float Wh_t[ND][PAD];   // [k][d]
    __shared__ __align__(16) float x_t[JT][PAD];    // [j][d]

    int b  = blockIdx.y;
    int j0 = blockIdx.x * JT;
    int t  = threadIdx.x;

    // stage W transposed (coalesced global reads)
#pragma unroll
    for (int r = 0; r < 16; ++r) {
        int e = t + r * 256;          // 0..4095, e = d*64 + k
        int d = e >> 6, k = e & 63;
        Ww_t[k][d] = W[e];
        Wh_t[k][d] = W[4096 + e];
    }
    // stage x tile transposed [j][d]
#pragma unroll
    for (int r = 0; r < 2; ++r) {
        int e = t + r * 256;          // 0..511
        int j = e & 7, d = e >> 3;
        x_t[j][d] = x[((size_t)(b * ND) + d) * NS + j0 + j];
    }
    __syncthreads();

    int k  = t & 63;
    int jq = t >> 6;                  // 0..3 ; thread handles j = j0+jq, j0+jq+4
    const float4* wa4 = (const float4*)&Ww_t[k][0];
    const float4* wh4 = (const float4*)&Wh_t[k][0];
    const float4* xa4 = (const float4*)&x_t[jq][0];
    const float4* xb4 = (const float4*)&x_t[jq + 4][0];

    float aa0 = 0.f, ba0 = 0.f, aa1 = 0.f, ba1 = 0.f;
#pragma unroll
    for (int d4 = 0; d4 < 16; ++d4) {
        float4 wa = wa4[d4], wh = wh4[d4];
        float4 xa = xa4[d4], xb = xb4[d4];
        aa0 = fmaf(xa.x, wa.x, fmaf(xa.y, wa.y, fmaf(xa.z, wa.z, fmaf(xa.w, wa.w, aa0))));
        ba0 = fmaf(xa.x, wh.x, fmaf(xa.y, wh.y, fmaf(xa.z, wh.z, fmaf(xa.w, wh.w, ba0))));
        aa1 = fmaf(xb.x, wa.x, fmaf(xb.y, wa.y, fmaf(xb.z, wa.z, fmaf(xb.w, wa.w, aa1))));
        ba1 = fmaf(xb.x, wh.x, fmaf(xb.y, wh.y, fmaf(xb.z, wh.z, fmaf(xb.w, wh.w, ba1))));
    }
    size_t r0 = ((size_t)b * NS + j0 + jq) * ND + k;
    size_t r1 = ((size_t)b * NS + j0 + jq + 4) * ND + k;
    a_ws[r0] = aa0;  a_ws[r1] = aa1;
    b_ws[r0] = ba0;  b_ws[r1] = ba1;
}

// ---------------------------------------------------------------------------
// Kernel 2: partial c over a w-chunk of 128, triangular-trimmed grid.
// part[c][b][d][i] = sum_{w in chunk, w>=i} x[b,d,w] * (-||a_i + b_w||)
// grid.x = 80 (trimmed (chunk,i-tile) pairs), grid.y = 8 (b)
// ---------------------------------------------------------------------------
__global__ __launch_bounds__(256) void k_c(const float* __restrict__ x,
                                           const float* __restrict__ a_ws,
                                           const float* __restrict__ b_ws,
                                           float* __restrict__ part) {
    __shared__ __align__(16) float a_t[TI][PAD];   // [i][k]
    __shared__ __align__(16) float b_t[64][PAD];   // [w][k]
    __shared__ __align__(16) float x_t[ND][PAD];   // [d][w]
    __shared__ __align__(16) float wm[TI][PAD];    // [i][w]  (= wmat-1, i.e. -n or 0)

    int b = blockIdx.y;
    int v = blockIdx.x;
    int cc, it0;
    if      (v < 8)  { cc = 0; it0 = v; }
    else if (v < 24) { cc = 1; it0 = v - 8; }
    else if (v < 48) { cc = 2; it0 = v - 24; }
    else             { cc = 3; it0 = v - 48; }
    int i0 = it0 * TI;
    int t  = threadIdx.x;

    // stage a tile [16][64] as float4
    {
        int i = t >> 4, k4 = t & 15;
        *((float4*)&a_t[i][0] + k4) =
            *((const float4*)&a_ws[((size_t)b * NS + i0 + i) * ND] + k4);
    }

    int i_loc  = t & 15;
    int wq     = t >> 4;              // 0..15
    int d_base = t >> 4;              // 0..15
    float acc[4] = {0.f, 0.f, 0.f, 0.f};

#pragma unroll
    for (int wt = 0; wt < 2; ++wt) {
        int w0 = cc * 128 + wt * 64;
        if (w0 + 63 < i0) continue;   // fully masked tile (block-uniform)

        __syncthreads();              // prev-iter consumers done (covers a_t stage too)

        // stage b_t[64][64] and x_t[64][64] as float4 (coalesced)
#pragma unroll
        for (int r = 0; r < 4; ++r) {
            int e  = t + r * 256;     // 0..1023
            int row = e >> 4, q4 = e & 15;
            *((float4*)&b_t[row][0] + q4) =
                *((const float4*)&b_ws[((size_t)b * NS + w0 + row) * ND] + q4);
            *((float4*)&x_t[row][0] + q4) =
                *((const float4*)&x[((size_t)b * ND + row) * NS + w0] + q4);
        }
        __syncthreads();

        // wmat tile: wm[i][w] = (i0+i <= w0+w) ? -||a_i + b_w|| : 0
        {
            float s[4] = {0.f, 0.f, 0.f, 0.f};
            const float4* a4 = (const float4*)&a_t[i_loc][0];
#pragma unroll
            for (int k4 = 0; k4 < 16; ++k4) {
                float4 av = a4[k4];
#pragma unroll
                for (int q = 0; q < 4; ++q) {
                    float4 bv = *((const float4*)&b_t[wq + 16 * q][0] + k4);
                    float ux = av.x + bv.x, uy = av.y + bv.y;
                    float uz = av.z + bv.z, uw = av.w + bv.w;
                    s[q] = fmaf(ux, ux, fmaf(uy, uy, fmaf(uz, uz, fmaf(uw, uw, s[q]))));
                }
            }
#pragma unroll
            for (int q = 0; q < 4; ++q) {
                int w = wq + 16 * q;
                wm[i_loc][w] = (i0 + i_loc <= w0 + w) ? -sqrtf(s[q]) : 0.f;
            }
        }
        __syncthreads();

        // accumulate partial c over this w tile (float4 along w)
        {
            const float4* wm4 = (const float4*)&wm[i_loc][0];
#pragma unroll
            for (int w4 = 0; w4 < 16; ++w4) {
                float4 wv = wm4[w4];
#pragma unroll
                for (int r = 0; r < 4; ++r) {
                    float4 xv = *((const float4*)&x_t[d_base + 16 * r][0] + w4);
                    acc[r] = fmaf(xv.x, wv.x,
                             fmaf(xv.y, wv.y,
                             fmaf(xv.z, wv.z,
                             fmaf(xv.w, wv.w, acc[r]))));
                }
            }
        }
    }

    // write partials: part[cc][b][d][i]
#pragma unroll
    for (int r = 0; r < 4; ++r) {
        int d = d_base + 16 * r;
        part[(((size_t)cc * NB + b) * ND + d) * NS + i0 + i_loc] = acc[r];
    }
}

// ---------------------------------------------------------------------------
// Kernel 3: c[b,d,i] = rowsum(x[b,d,:]) + sum over live chunks of part[p][b][d][i]
// Block: one (b,d) row. 256 threads.
// ---------------------------------------------------------------------------
__global__ __launch_bounds__(256) void k_red(const float* __restrict__ x,
                                             const float* __restrict__ part,
                                             float* __restrict__ out) {
    __shared__ float red[4];
    int b = blockIdx.y, d = blockIdx.x, t = threadIdx.x;
    const float* xr = x + ((size_t)b * ND + d) * NS;

    float s = xr[t] + xr[t + 256];
#pragma unroll
    for (int m = 32; m >= 1; m >>= 1) s += __shfl_xor(s, m, 64);
    if ((t & 63) == 0) red[t >> 6] = s;
    __syncthreads();
    float rs = red[0] + red[1] + red[2] + red[3];

#pragma unroll
    for (int r = 0; r < 2; ++r) {
        int i  = t + r * 256;
        int ia = i & ~(TI - 1);       // i-tile base
        float v = rs;
#pragma unroll
        for (int p = 0; p < 4; ++p) {
            if (ia <= 128 * p + 127)  // slot (p, i-tile) was live & written
                v += part[(((size_t)p * NB + b) * ND + d) * NS + i];
        }
        out[((size_t)b * ND + d) * NS + i] = v;
    }
}

extern "C" void kernel_launch(void* const* d_in, const int* in_sizes, int n_in,
                              void* d_out, int out_size, void* d_ws, size_t ws_size,
                              hipStream_t stream) {
    const float* x = (const float*)d_in[0];
    const float* W = (const float*)d_in[1];
    float* out  = (float*)d_out;
    float* a_ws = (float*)d_ws;                                  // 1 MB
    float* b_ws = a_ws + (size_t)NB * NS * ND;                   // 1 MB
    float* part = b_ws + (size_t)NB * NS * ND;                   // 4 MB

    k_ab<<<dim3(NS / JT, NB), dim3(256), 0, stream>>>(x, W, a_ws, b_ws);
    k_c <<<dim3(80, NB),      dim3(256), 0, stream>>>(x, a_ws, b_ws, part);
    k_red<<<dim3(ND, NB),     dim3(256), 0, stream>>>(x, part, out);
}

// Round 4
// 36.532 us; speedup vs baseline: 1.5049x; 1.0294x over previous
//
#include <hip/hip_runtime.h>
#include <math.h>

#define NB 8
#define ND 64
#define NS 512
#define JT 8
#define PAD 68

typedef __attribute__((ext_vector_type(8))) short bf16x8;
typedef __attribute__((ext_vector_type(4))) float f32x4;
typedef __attribute__((ext_vector_type(4))) unsigned short us4;
typedef __attribute__((ext_vector_type(8))) unsigned short us8;

__device__ __forceinline__ unsigned short f2bf(float f) {
    unsigned int u = __float_as_uint(f);
    unsigned int r = (u + 0x7FFFu + ((u >> 16) & 1u)) >> 16;   // RNE
    return (unsigned short)r;
}

// ---------------------------------------------------------------------------
// Kernel 1: blocks x<64: a/b GEMM -> a_bf,b_bf (bf16) + na,nb (||row||^2).
//           blocks x>=64: x -> x_bf (bf16) AND out[b,d,:] = rowsum(x[b,d,:]).
// ---------------------------------------------------------------------------
__global__ __launch_bounds__(256) void k_ab(const float* __restrict__ x,
                                            const float* __restrict__ W,
                                            unsigned short* __restrict__ a_bf,
                                            unsigned short* __restrict__ b_bf,
                                            float* __restrict__ na,
                                            float* __restrict__ nb,
                                            unsigned short* __restrict__ x_bf,
                                            float* __restrict__ out) {
    __shared__ __align__(16) float Ww_t[ND][PAD];
    __shared__ __align__(16) float Wh_t[ND][PAD];
    __shared__ __align__(16) float x_t[JT][PAD];

    int b  = blockIdx.y;
    int bx = blockIdx.x;
    int t  = threadIdx.x;

    if (bx >= NS / JT) {
        // ---- init blocks: x_bf convert + out rowsum-init ----
        int e    = bx - NS / JT;          // 0..7
        int wv   = t >> 6;
        int lane = t & 63;
#pragma unroll
        for (int rr = 0; rr < 2; ++rr) {
            int d = e * 8 + wv * 2 + rr;
            const float4* xr4 = (const float4*)(x + ((size_t)(b * ND + d)) * NS);
            float4 v0 = xr4[2 * lane];
            float4 v1 = xr4[2 * lane + 1];
            float s = v0.x + v0.y + v0.z + v0.w + v1.x + v1.y + v1.z + v1.w;
#pragma unroll
            for (int m = 32; m >= 1; m >>= 1) s += __shfl_xor(s, m, 64);
            // bf16 row
            us8 h;
            h[0] = f2bf(v0.x); h[1] = f2bf(v0.y); h[2] = f2bf(v0.z); h[3] = f2bf(v0.w);
            h[4] = f2bf(v1.x); h[5] = f2bf(v1.y); h[6] = f2bf(v1.z); h[7] = f2bf(v1.w);
            *(us8*)(x_bf + ((size_t)(b * ND + d)) * NS + lane * 8) = h;
            // out init = rowsum
            float4 rsv = make_float4(s, s, s, s);
            float4* o4 = (float4*)(out + ((size_t)(b * ND + d)) * NS);
            o4[2 * lane]     = rsv;
            o4[2 * lane + 1] = rsv;
        }
        return;
    }

    // ---- a/b GEMM blocks ----
    int j0 = bx * JT;
#pragma unroll
    for (int r = 0; r < 16; ++r) {
        int e = t + r * 256;
        int d = e >> 6, k = e & 63;
        Ww_t[k][d] = W[e];
        Wh_t[k][d] = W[4096 + e];
    }
#pragma unroll
    for (int r = 0; r < 2; ++r) {
        int e = t + r * 256;
        int j = e & 7, d = e >> 3;
        x_t[j][d] = x[((size_t)(b * ND) + d) * NS + j0 + j];
    }
    __syncthreads();

    int k  = t & 63;
    int jq = t >> 6;
    const float4* wa4 = (const float4*)&Ww_t[k][0];
    const float4* wh4 = (const float4*)&Wh_t[k][0];
    const float4* xa4 = (const float4*)&x_t[jq][0];
    const float4* xb4 = (const float4*)&x_t[jq + 4][0];

    float aa0 = 0.f, ba0 = 0.f, aa1 = 0.f, ba1 = 0.f;
#pragma unroll
    for (int d4 = 0; d4 < 16; ++d4) {
        float4 wa = wa4[d4], wh = wh4[d4];
        float4 xa = xa4[d4], xb = xb4[d4];
        aa0 = fmaf(xa.x, wa.x, fmaf(xa.y, wa.y, fmaf(xa.z, wa.z, fmaf(xa.w, wa.w, aa0))));
        ba0 = fmaf(xa.x, wh.x, fmaf(xa.y, wh.y, fmaf(xa.z, wh.z, fmaf(xa.w, wh.w, ba0))));
        aa1 = fmaf(xb.x, wa.x, fmaf(xb.y, wa.y, fmaf(xb.z, wa.z, fmaf(xb.w, wa.w, aa1))));
        ba1 = fmaf(xb.x, wh.x, fmaf(xb.y, wh.y, fmaf(xb.z, wh.z, fmaf(xb.w, wh.w, ba1))));
    }
    size_t r0 = ((size_t)b * NS + j0 + jq) * ND + k;
    size_t r1 = ((size_t)b * NS + j0 + jq + 4) * ND + k;
    a_bf[r0] = f2bf(aa0);  a_bf[r1] = f2bf(aa1);
    b_bf[r0] = f2bf(ba0);  b_bf[r1] = f2bf(ba1);

    float sa0 = aa0 * aa0, sa1 = aa1 * aa1, sb0 = ba0 * ba0, sb1 = ba1 * ba1;
#pragma unroll
    for (int m = 32; m >= 1; m >>= 1) {
        sa0 += __shfl_xor(sa0, m, 64);
        sa1 += __shfl_xor(sa1, m, 64);
        sb0 += __shfl_xor(sb0, m, 64);
        sb1 += __shfl_xor(sb1, m, 64);
    }
    if (k == 0) {
        na[b * NS + j0 + jq]     = sa0;
        na[b * NS + j0 + jq + 4] = sa1;
        nb[b * NS + j0 + jq]     = sb0;
        nb[b * NS + j0 + jq + 4] = sb1;
    }
}

// ---------------------------------------------------------------------------
// Kernel 2: per live 64x64 (i-tile, w-tile):
//   S[w][i] = b_bf[w,:]·a_bf[i,:]   (MFMA, K=64)
//   wm[i][w] = (i<=w) ? -sqrt(na_i + nb_w + 2S) : 0  -> bf16 -> swizzled LDS
//   partial c^T[i][d] = wm[i,:]·x_bf[d,:]  (MFMA, K=64) -> atomicAdd out
// ---------------------------------------------------------------------------
__global__ __launch_bounds__(256) void k_c(const unsigned short* __restrict__ x_bf,
                                           const unsigned short* __restrict__ a_bf,
                                           const unsigned short* __restrict__ b_bf,
                                           const float* __restrict__ na,
                                           const float* __restrict__ nb,
                                           float* __restrict__ out) {
    __shared__ unsigned short wm_lds[64 * 64];

    int b = blockIdx.y;
    int v = blockIdx.x;
    int u = 0;
    while ((u + 1) * (u + 2) / 2 <= v) ++u;   // w-tile index
    int ti = v - u * (u + 1) / 2;             // i-tile index (ti <= u)
    int i0 = ti * 64, w0 = u * 64;

    int t = threadIdx.x;
    int lane = t & 63, wv = t >> 6;
    int c = lane & 15, g = lane >> 4;

    // --- fragment loads (issued together to overlap L2 latency) ---
    bf16x8 afrag[2], bfrag[4][2], xfrag[4][2];
    {
        const unsigned short* bb = b_bf + ((size_t)(b * NS + w0 + 16 * wv + c)) * ND + g * 8;
        afrag[0] = *(const bf16x8*)(bb);
        afrag[1] = *(const bf16x8*)(bb + 32);
    }
#pragma unroll
    for (int n = 0; n < 4; ++n) {
        const unsigned short* aa = a_bf + ((size_t)(b * NS + i0 + 16 * n + c)) * ND + g * 8;
        bfrag[n][0] = *(const bf16x8*)(aa);
        bfrag[n][1] = *(const bf16x8*)(aa + 32);
    }
#pragma unroll
    for (int nd = 0; nd < 4; ++nd) {
        const unsigned short* xx = x_bf + ((size_t)(b * ND + 16 * nd + c)) * NS + w0 + 8 * g;
        xfrag[nd][0] = *(const bf16x8*)(xx);
        xfrag[nd][1] = *(const bf16x8*)(xx + 32);
    }
    float nbv[4], nav[4];
#pragma unroll
    for (int r = 0; r < 4; ++r) nbv[r] = nb[b * NS + w0 + 16 * wv + 4 * g + r];
#pragma unroll
    for (int n = 0; n < 4; ++n) nav[n] = na[b * NS + i0 + 16 * n + c];

    // --- GEMM1 + wm -> LDS ---
    int wbase = w0 + 16 * wv + 4 * g;         // global w of reg r = wbase + r
#pragma unroll
    for (int n = 0; n < 4; ++n) {
        f32x4 acc = {0.f, 0.f, 0.f, 0.f};
        acc = __builtin_amdgcn_mfma_f32_16x16x32_bf16(afrag[0], bfrag[n][0], acc, 0, 0, 0);
        acc = __builtin_amdgcn_mfma_f32_16x16x32_bf16(afrag[1], bfrag[n][1], acc, 0, 0, 0);
        int i_loc  = 16 * n + c;
        int i_glob = i0 + i_loc;
        us4 pk;
#pragma unroll
        for (int r = 0; r < 4; ++r) {
            float s2 = nav[n] + nbv[r] + 2.f * acc[r];
            float val = (i_glob <= wbase + r) ? -sqrtf(fmaxf(s2, 0.f)) : 0.f;
            pk[r] = f2bf(val);
        }
        // wm_lds[i][w], 16B-block XOR swizzle: h(i,w) = i*64 + ((w>>3 ^ i&7)<<3) + (w&7)
        int wblk = 2 * wv + (g >> 1);
        int hidx = i_loc * 64 + ((wblk ^ (i_loc & 7)) << 3) + 4 * (g & 1);
        *(us4*)(&wm_lds[hidx]) = pk;
    }
    __syncthreads();

    // --- GEMM2: c^T[i][d] partial, then atomic accumulate ---
    bf16x8 a2[2];
    {
        int i_loc = 16 * wv + c;
#pragma unroll
        for (int s = 0; s < 2; ++s)
            a2[s] = *(const bf16x8*)(&wm_lds[i_loc * 64 + (((4 * s + g) ^ (i_loc & 7)) << 3)]);
    }
#pragma unroll
    for (int nd = 0; nd < 4; ++nd) {
        f32x4 acc = {0.f, 0.f, 0.f, 0.f};
        acc = __builtin_amdgcn_mfma_f32_16x16x32_bf16(a2[0], xfrag[nd][0], acc, 0, 0, 0);
        acc = __builtin_amdgcn_mfma_f32_16x16x32_bf16(a2[1], xfrag[nd][1], acc, 0, 0, 0);
        int d = 16 * nd + c;
        float* op = out + ((size_t)(b * ND + d)) * NS + i0 + 16 * wv + 4 * g;
#pragma unroll
        for (int r = 0; r < 4; ++r) atomicAdd(op + r, acc[r]);
    }
}

extern "C" void kernel_launch(void* const* d_in, const int* in_sizes, int n_in,
                              void* d_out, int out_size, void* d_ws, size_t ws_size,
                              hipStream_t stream) {
    const float* x = (const float*)d_in[0];
    const float* W = (const float*)d_in[1];
    float* out = (float*)d_out;

    unsigned short* a_bf = (unsigned short*)d_ws;            // 512 KB
    unsigned short* b_bf = a_bf + (size_t)NB * NS * ND;      // 512 KB
    unsigned short* x_bf = b_bf + (size_t)NB * NS * ND;      // 512 KB
    float* na_p = (float*)(x_bf + (size_t)NB * NS * ND);     // 16 KB
    float* nb_p = na_p + NB * NS;                            // 16 KB

    k_ab<<<dim3(NS / JT + 8, NB), dim3(256), 0, stream>>>(x, W, a_bf, b_bf, na_p, nb_p, x_bf, out);
    k_c <<<dim3(36, NB),          dim3(256), 0, stream>>>(x_bf, a_bf, b_bf, na_p, nb_p, out);
}

// Round 5
// 26.343 us; speedup vs baseline: 2.0870x; 1.3868x over previous
//
#include <hip/hip_runtime.h>
#include <math.h>

#define NB 8
#define ND 64
#define NS 512
#define JT 8
#define PAD 68

typedef __attribute__((ext_vector_type(8))) short bf16x8;
typedef __attribute__((ext_vector_type(4))) float f32x4;
typedef __attribute__((ext_vector_type(4))) unsigned short us4;
typedef __attribute__((ext_vector_type(8))) unsigned short us8;

__device__ __forceinline__ unsigned short f2bf(float f) {
    unsigned int u = __float_as_uint(f);
    unsigned int r = (u + 0x7FFFu + ((u >> 16) & 1u)) >> 16;   // RNE
    return (unsigned short)r;
}

// ---------------------------------------------------------------------------
// Kernel 1: blocks x<64: a/b GEMM -> a_bf,b_bf (bf16) + na,nb (||row||^2).
//           blocks x>=64: x -> x_bf (bf16) + rs[b][d] = rowsum(x[b,d,:]).
// ---------------------------------------------------------------------------
__global__ __launch_bounds__(256) void k_ab(const float* __restrict__ x,
                                            const float* __restrict__ W,
                                            unsigned short* __restrict__ a_bf,
                                            unsigned short* __restrict__ b_bf,
                                            float* __restrict__ na,
                                            float* __restrict__ nb,
                                            unsigned short* __restrict__ x_bf,
                                            float* __restrict__ rs) {
    __shared__ __align__(16) float Ww_t[ND][PAD];
    __shared__ __align__(16) float Wh_t[ND][PAD];
    __shared__ __align__(16) float x_t[JT][PAD];

    int b  = blockIdx.y;
    int bx = blockIdx.x;
    int t  = threadIdx.x;

    if (bx >= NS / JT) {
        // ---- init blocks: x_bf convert + rowsum ----
        int e    = bx - NS / JT;          // 0..7
        int wv   = t >> 6;
        int lane = t & 63;
#pragma unroll
        for (int rr = 0; rr < 2; ++rr) {
            int d = e * 8 + wv * 2 + rr;
            const float4* xr4 = (const float4*)(x + ((size_t)(b * ND + d)) * NS);
            float4 v0 = xr4[2 * lane];
            float4 v1 = xr4[2 * lane + 1];
            float s = v0.x + v0.y + v0.z + v0.w + v1.x + v1.y + v1.z + v1.w;
#pragma unroll
            for (int m = 32; m >= 1; m >>= 1) s += __shfl_xor(s, m, 64);
            us8 h;
            h[0] = f2bf(v0.x); h[1] = f2bf(v0.y); h[2] = f2bf(v0.z); h[3] = f2bf(v0.w);
            h[4] = f2bf(v1.x); h[5] = f2bf(v1.y); h[6] = f2bf(v1.z); h[7] = f2bf(v1.w);
            *(us8*)(x_bf + ((size_t)(b * ND + d)) * NS + lane * 8) = h;
            if (lane == 0) rs[b * ND + d] = s;
        }
        return;
    }

    // ---- a/b GEMM blocks ----
    int j0 = bx * JT;
#pragma unroll
    for (int r = 0; r < 16; ++r) {
        int e = t + r * 256;
        int d = e >> 6, k = e & 63;
        Ww_t[k][d] = W[e];
        Wh_t[k][d] = W[4096 + e];
    }
#pragma unroll
    for (int r = 0; r < 2; ++r) {
        int e = t + r * 256;
        int j = e & 7, d = e >> 3;
        x_t[j][d] = x[((size_t)(b * ND) + d) * NS + j0 + j];
    }
    __syncthreads();

    int k  = t & 63;
    int jq = t >> 6;
    const float4* wa4 = (const float4*)&Ww_t[k][0];
    const float4* wh4 = (const float4*)&Wh_t[k][0];
    const float4* xa4 = (const float4*)&x_t[jq][0];
    const float4* xb4 = (const float4*)&x_t[jq + 4][0];

    float aa0 = 0.f, ba0 = 0.f, aa1 = 0.f, ba1 = 0.f;
#pragma unroll
    for (int d4 = 0; d4 < 16; ++d4) {
        float4 wa = wa4[d4], wh = wh4[d4];
        float4 xa = xa4[d4], xb = xb4[d4];
        aa0 = fmaf(xa.x, wa.x, fmaf(xa.y, wa.y, fmaf(xa.z, wa.z, fmaf(xa.w, wa.w, aa0))));
        ba0 = fmaf(xa.x, wh.x, fmaf(xa.y, wh.y, fmaf(xa.z, wh.z, fmaf(xa.w, wh.w, ba0))));
        aa1 = fmaf(xb.x, wa.x, fmaf(xb.y, wa.y, fmaf(xb.z, wa.z, fmaf(xb.w, wa.w, aa1))));
        ba1 = fmaf(xb.x, wh.x, fmaf(xb.y, wh.y, fmaf(xb.z, wh.z, fmaf(xb.w, wh.w, ba1))));
    }
    size_t r0 = ((size_t)b * NS + j0 + jq) * ND + k;
    size_t r1 = ((size_t)b * NS + j0 + jq + 4) * ND + k;
    a_bf[r0] = f2bf(aa0);  a_bf[r1] = f2bf(aa1);
    b_bf[r0] = f2bf(ba0);  b_bf[r1] = f2bf(ba1);

    float sa0 = aa0 * aa0, sa1 = aa1 * aa1, sb0 = ba0 * ba0, sb1 = ba1 * ba1;
#pragma unroll
    for (int m = 32; m >= 1; m >>= 1) {
        sa0 += __shfl_xor(sa0, m, 64);
        sa1 += __shfl_xor(sa1, m, 64);
        sb0 += __shfl_xor(sb0, m, 64);
        sb1 += __shfl_xor(sb1, m, 64);
    }
    if (k == 0) {
        na[b * NS + j0 + jq]     = sa0;
        na[b * NS + j0 + jq + 4] = sa1;
        nb[b * NS + j0 + jq]     = sb0;
        nb[b * NS + j0 + jq + 4] = sb1;
    }
}

// ---------------------------------------------------------------------------
// Kernel 2: per live 64x64 (i-tile ti, w-tile u):
//   S[w][i] = b_bf[w,:]·a_bf[i,:]   (MFMA, K=64)
//   wm[i][w] = (i<=w) ? -sqrt(na_i + nb_w + 2S) : 0  -> bf16 -> swizzled LDS
//   part[u][b][d][i-tile] = wm[i,:]·x_bf[d,:]  (MFMA, K=64), disjoint stores
// ---------------------------------------------------------------------------
__global__ __launch_bounds__(256) void k_c(const unsigned short* __restrict__ x_bf,
                                           const unsigned short* __restrict__ a_bf,
                                           const unsigned short* __restrict__ b_bf,
                                           const float* __restrict__ na,
                                           const float* __restrict__ nb,
                                           float* __restrict__ part) {
    __shared__ unsigned short wm_lds[64 * 64];

    int b = blockIdx.y;
    int v = blockIdx.x;
    int u = 0;
    while ((u + 1) * (u + 2) / 2 <= v) ++u;   // w-tile index
    int ti = v - u * (u + 1) / 2;             // i-tile index (ti <= u)
    int i0 = ti * 64, w0 = u * 64;

    int t = threadIdx.x;
    int lane = t & 63, wv = t >> 6;
    int c = lane & 15, g = lane >> 4;

    // --- fragment loads (issued together to overlap L2 latency) ---
    bf16x8 afrag[2], bfrag[4][2], xfrag[4][2];
    {
        const unsigned short* bb = b_bf + ((size_t)(b * NS + w0 + 16 * wv + c)) * ND + g * 8;
        afrag[0] = *(const bf16x8*)(bb);
        afrag[1] = *(const bf16x8*)(bb + 32);
    }
#pragma unroll
    for (int n = 0; n < 4; ++n) {
        const unsigned short* aa = a_bf + ((size_t)(b * NS + i0 + 16 * n + c)) * ND + g * 8;
        bfrag[n][0] = *(const bf16x8*)(aa);
        bfrag[n][1] = *(const bf16x8*)(aa + 32);
    }
#pragma unroll
    for (int nd = 0; nd < 4; ++nd) {
        const unsigned short* xx = x_bf + ((size_t)(b * ND + 16 * nd + c)) * NS + w0 + 8 * g;
        xfrag[nd][0] = *(const bf16x8*)(xx);
        xfrag[nd][1] = *(const bf16x8*)(xx + 32);
    }
    float nbv[4], nav[4];
#pragma unroll
    for (int r = 0; r < 4; ++r) nbv[r] = nb[b * NS + w0 + 16 * wv + 4 * g + r];
#pragma unroll
    for (int n = 0; n < 4; ++n) nav[n] = na[b * NS + i0 + 16 * n + c];

    // --- GEMM1 + wm -> LDS ---
    int wbase = w0 + 16 * wv + 4 * g;
#pragma unroll
    for (int n = 0; n < 4; ++n) {
        f32x4 acc = {0.f, 0.f, 0.f, 0.f};
        acc = __builtin_amdgcn_mfma_f32_16x16x32_bf16(afrag[0], bfrag[n][0], acc, 0, 0, 0);
        acc = __builtin_amdgcn_mfma_f32_16x16x32_bf16(afrag[1], bfrag[n][1], acc, 0, 0, 0);
        int i_loc  = 16 * n + c;
        int i_glob = i0 + i_loc;
        us4 pk;
#pragma unroll
        for (int r = 0; r < 4; ++r) {
            float s2 = nav[n] + nbv[r] + 2.f * acc[r];
            float val = (i_glob <= wbase + r) ? -sqrtf(fmaxf(s2, 0.f)) : 0.f;
            pk[r] = f2bf(val);
        }
        int wblk = 2 * wv + (g >> 1);
        int hidx = i_loc * 64 + ((wblk ^ (i_loc & 7)) << 3) + 4 * (g & 1);
        *(us4*)(&wm_lds[hidx]) = pk;
    }
    __syncthreads();

    // --- GEMM2: partial c^T tile, disjoint float4 stores ---
    bf16x8 a2[2];
    {
        int i_loc = 16 * wv + c;
#pragma unroll
        for (int s = 0; s < 2; ++s)
            a2[s] = *(const bf16x8*)(&wm_lds[i_loc * 64 + (((4 * s + g) ^ (i_loc & 7)) << 3)]);
    }
#pragma unroll
    for (int nd = 0; nd < 4; ++nd) {
        f32x4 acc = {0.f, 0.f, 0.f, 0.f};
        acc = __builtin_amdgcn_mfma_f32_16x16x32_bf16(a2[0], xfrag[nd][0], acc, 0, 0, 0);
        acc = __builtin_amdgcn_mfma_f32_16x16x32_bf16(a2[1], xfrag[nd][1], acc, 0, 0, 0);
        int d = 16 * nd + c;
        float* pp = part + (((size_t)u * NB + b) * ND + d) * NS + i0 + 16 * wv + 4 * g;
        *(f32x4*)pp = acc;
    }
}

// ---------------------------------------------------------------------------
// Kernel 3: out[b,d,i] = rs[b,d] + sum_{u >= i>>6} part[u][b][d][i]
// ---------------------------------------------------------------------------
__global__ __launch_bounds__(256) void k_red(const float* __restrict__ rs,
                                             const float* __restrict__ part,
                                             float* __restrict__ out) {
    int b = blockIdx.y, d = blockIdx.x, t = threadIdx.x;
    float r = rs[b * ND + d];
#pragma unroll
    for (int q = 0; q < 2; ++q) {
        int i  = t + q * 256;
        int it = i >> 6;
        float v = r;
#pragma unroll
        for (int u = 0; u < 8; ++u) {
            if (u >= it)
                v += part[(((size_t)u * NB + b) * ND + d) * NS + i];
        }
        out[((size_t)b * ND + d) * NS + i] = v;
    }
}

extern "C" void kernel_launch(void* const* d_in, const int* in_sizes, int n_in,
                              void* d_out, int out_size, void* d_ws, size_t ws_size,
                              hipStream_t stream) {
    const float* x = (const float*)d_in[0];
    const float* W = (const float*)d_in[1];
    float* out = (float*)d_out;

    unsigned short* a_bf = (unsigned short*)d_ws;            // 512 KB
    unsigned short* b_bf = a_bf + (size_t)NB * NS * ND;      // 512 KB
    unsigned short* x_bf = b_bf + (size_t)NB * NS * ND;      // 512 KB
    float* na_p = (float*)(x_bf + (size_t)NB * NS * ND);     // 16 KB
    float* nb_p = na_p + NB * NS;                            // 16 KB
    float* rs_p = nb_p + NB * NS;                            // 2 KB
    float* part = rs_p + NB * ND;                            // 8 MB

    k_ab<<<dim3(NS / JT + 8, NB), dim3(256), 0, stream>>>(x, W, a_bf, b_bf, na_p, nb_p, x_bf, rs_p);
    k_c <<<dim3(36, NB),          dim3(256), 0, stream>>>(x_bf, a_bf, b_bf, na_p, nb_p, part);
    k_red<<<dim3(ND, NB),         dim3(256), 0, stream>>>(rs_p, part, out);
}